// Round 10
// baseline (205.326 us; speedup 1.0000x reference)
//
#include <hip/hip_runtime.h>
#include <hip/hip_bf16.h>

typedef __bf16 bf16;
typedef __bf16 bf16x4 __attribute__((ext_vector_type(4)));
typedef __bf16 bf16x8 __attribute__((ext_vector_type(8)));
typedef float  f32x4  __attribute__((ext_vector_type(4)));

#define T_SZ   4096
#define NFREQ  512
#define HOP    512
#define OUT_LEN 2097664   // 4097 * 512
#define NTT33  33
#define XROWS  4097       // Xw row t holds Y[:,t], t in [0,4096]

#define XW_ELEMS ((size_t)16 * XROWS * 1024)
#define WT_ELEMS ((size_t)512 * 1024)
#define WS_NEED  ((XW_ELEMS + WT_ELEMS) * 2)

__device__ __forceinline__ void gl16(const void* g, void* l) {
    __builtin_amdgcn_global_load_lds(
        (const __attribute__((address_space(1))) void*)g,
        (__attribute__((address_space(3))) void*)l, 16, 0, 0);
}

// Symmetry: W[j+512,c] = (-1)^(c+1) W[j,c].  With Y[k,t] = x[k,t] + s_k x[k,t-1],
// s_k = (c odd ? +1 : -1), c = k mod 512:  out[t*512+j] = (W[j,:]·Y[:,t] + ac[t] + ac[t-1])/1024.
// Single 512x1024xT GEMM — half the FLOPs of the lo/hi formulation.

// ---------- Wt[j][k] = k<512 ? rk[j][k] : ik[j][k-512], j in [0,512) ----------
__global__ __launch_bounds__(256, 4) void cvt_w(const float* __restrict__ rk,
                                                const float* __restrict__ ik,
                                                bf16* __restrict__ Wt) {
    const int j  = blockIdx.x;           // 512
    const int k4 = threadIdx.x * 4;
    const float* s = (k4 < NFREQ) ? &rk[j * NFREQ + k4] : &ik[j * NFREQ + k4 - NFREQ];
    f32x4 v = *(const f32x4*)s;
    bf16x4 h;
    h[0] = (bf16)v[0]; h[1] = (bf16)v[1]; h[2] = (bf16)v[2]; h[3] = (bf16)v[3];
    *(bf16x4*)&Wt[((size_t)j << 10) + k4] = h;
}

// ---------- Xw[b][t][k] = Y[k,t]  (transpose + bf16 + the s_k combine) ----------
__global__ __launch_bounds__(256, 4) void cvt_x(const float* __restrict__ magn,
                                                const float* __restrict__ phase,
                                                bf16* __restrict__ Xw) {
    __shared__ float t2[64][133];        // cols 0..127 = x[t0..t0+127], col 128 = x[t0-1]
    const int tid = threadIdx.x;
    const int bid = blockIdx.x;
    const int kt  = bid & 15;            // k-tile of 64 (global k = kt*64 + f)
    const int tt  = (bid >> 4) & 31;     // t-tile of 128
    const int b   = bid >> 9;
    const float* srcb = (kt < 8 ? magn : phase)
                      + ((size_t)b * NFREQ + (kt & 7) * 64) * T_SZ + tt * 128;
    const int fr = tid >> 5;
    const int cc = (tid & 31) * 4;
    #pragma unroll
    for (int p = 0; p < 8; ++p) {
        const int f = fr + 8 * p;
        f32x4 v = *(const f32x4*)&srcb[(size_t)f * T_SZ + cc];
        t2[f][cc + 0] = v[0]; t2[f][cc + 1] = v[1];
        t2[f][cc + 2] = v[2]; t2[f][cc + 3] = v[3];
    }
    if (tid < 64)
        t2[tid][128] = (tt > 0) ? srcb[(size_t)tid * T_SZ - 1] : 0.f;
    __syncthreads();

    const int koff = (tid & 7) * 8;      // local k base
    bf16* dstb = Xw + (((size_t)b * XROWS + tt * 128) << 10) + kt * 64 + koff;
    #pragma unroll
    for (int q = 0; q < 4; ++q) {
        const int tr  = (tid >> 3) + 32 * q;
        const int im1 = tr ? (tr - 1) : 128;
        bf16x8 o;
        #pragma unroll
        for (int ki = 0; ki < 8; ++ki) {
            const int f = koff + ki;
            const float sgn = (f & 1) ? 1.f : -1.f;   // c parity == f parity
            o[ki] = (bf16)(t2[f][tr] + sgn * t2[f][im1]);
        }
        *(bf16x8*)&dstb[(size_t)tr << 10] = o;
    }
    // row t = 4096: Y = s_k * x[k, 4095]  (x[:,4096] = 0)
    if (tt == 31 && tid < 8) {
        bf16x8 o;
        #pragma unroll
        for (int ki = 0; ki < 8; ++ki) {
            const int f = tid * 8 + ki;
            const float sgn = (f & 1) ? 1.f : -1.f;
            o[ki] = (bf16)(sgn * t2[f][127]);
        }
        *(bf16x8*)&Xw[(((size_t)b * XROWS + 4096) << 10) + kt * 64 + tid * 8] = o;
    }
}

// ---------- main GEMM: 128j x 128t tile, 4 waves, 4 blocks/CU, 2-barrier loop ----------
// A-tile: 128 rows = Wt[j0+r].  B-tile row r = Y[:, t0+r], r in [0,128), all t valid (<=4095).
// Swizzle both-sides: 16B slot' = slot ^ ((row ^ row>>2)&3); LDS linear dest,
// gl16 SOURCE pre-swizzled, ds_read applies the same XOR.
// Grid 2048 = exactly 2 residency rounds at 4 blocks/CU (1024 capacity) - no tail round.
__global__ __launch_bounds__(256, 4) void istft_gemmY2(
    const bf16* __restrict__ Xw, const bf16* __restrict__ Wt,
    const float* __restrict__ acv, float* __restrict__ out)
{
    __shared__ __attribute__((aligned(16))) bf16 As[2][128 * 32];
    __shared__ __attribute__((aligned(16))) bf16 Bs[2][128 * 32];

    const int tid = threadIdx.x;
    const int w   = tid >> 6;      // 4 waves: wr = w>>1 (j half), wc = w&1 (t half)
    const int l   = tid & 63;
    const int wr  = w >> 1, wc = w & 1;
    const int c15 = l & 15, c4 = l >> 4;

    const int bid = blockIdx.x;    // 2048 = 512 panels x 4 j-tiles; panel -> xcd = bid&7
    const int xcd = bid & 7;
    const int jt  = (bid >> 3) & 3;
    const int pg  = bid >> 5;      // 0..63
    const int pnl = pg * 8 + xcd;  // 0..511
    const int b   = pnl >> 5;
    const int tt0 = pnl & 31;
    const int j0  = jt * 128;
    const int t0  = tt0 * 128;
    const size_t xb = (size_t)b * XROWS;

    // staging: 64B rows of 4 slots; lane -> row 16w+(l>>2), slot l&3, pre-swizzled src slot
    const int ssrc = ((l & 3) ^ ((l >> 2) & 3) ^ ((l >> 4) & 3)) * 8;
    const int srow = 16 * w + (l >> 2);                 // 0..63 per sweep

    const size_t asrc0 = ((size_t)(j0 + srow)) << 10;        // A rows 0..63
    const size_t asrc1 = ((size_t)(j0 + 64 + srow)) << 10;   // A rows 64..127
    const size_t bsrc0 = (xb + t0 + srow) << 10;             // B rows 0..63
    const size_t bsrc1 = (xb + t0 + 64 + srow) << 10;        // B rows 64..127

    auto stage = [&](int p, int ks) {
        const int k0 = ks * 32;
        gl16(Wt + asrc0 + k0 + ssrc, &As[p][(16 * w) * 32]);
        gl16(Wt + asrc1 + k0 + ssrc, &As[p][(64 + 16 * w) * 32]);
        gl16(Xw + bsrc0 + k0 + ssrc, &Bs[p][(16 * w) * 32]);
        gl16(Xw + bsrc1 + k0 + ssrc, &Bs[p][(64 + 16 * w) * 32]);
    };

    f32x4 acc[4][4];
    #pragma unroll
    for (int i = 0; i < 4; ++i)
        #pragma unroll
        for (int j = 0; j < 4; ++j)
            acc[i][j] = (f32x4){0.f, 0.f, 0.f, 0.f};

    bf16x8 a[4], bb[4];
    auto rdFrags = [&](int p) {
        #pragma unroll
        for (int m = 0; m < 4; ++m) {
            const int r = wr * 64 + m * 16 + c15;            // 0..127
            const int s = ((c4 ^ r ^ (r >> 2)) & 3) * 8;
            a[m] = *(const bf16x8*)&As[p][r * 32 + s];
        }
        #pragma unroll
        for (int n = 0; n < 4; ++n) {
            const int r = wc * 64 + n * 16 + c15;            // 0..127
            const int s = ((c4 ^ r ^ (r >> 2)) & 3) * 8;
            bb[n] = *(const bf16x8*)&Bs[p][r * 32 + s];
        }
    };

    stage(0, 0);
    __syncthreads();

    for (int ks = 0; ks < 32; ++ks) {
        const int P = ks & 1;
        if (ks + 1 < 32) stage(P ^ 1, ks + 1);   // issue next-tile loads first
        rdFrags(P);
        #pragma unroll
        for (int m = 0; m < 4; ++m)
            #pragma unroll
            for (int n = 0; n < 4; ++n)
                acc[m][n] = __builtin_amdgcn_mfma_f32_16x16x32_bf16(
                    a[m], bb[n], acc[m][n], 0, 0, 0);
        __syncthreads();   // drains staging loads; hidden by 4 blocks/CU
    }

    // epilogue: out[tt*512+j] = (acc + ac[tt] + ac[tt-1]) / 1024
    const float inv = 1.0f / 1024.0f;
    float* ob = out + (size_t)b * OUT_LEN;
    const float* acb = acv + (size_t)b * T_SZ;
    const int jbase = j0 + wr * 64 + c4 * 4;
    #pragma unroll
    for (int n = 0; n < 4; ++n) {
        const int tt = t0 + wc * 64 + n * 16 + c15;          // 0..4095
        const float acs = acb[tt] + (tt ? acb[tt - 1] : 0.f);
        #pragma unroll
        for (int m = 0; m < 4; ++m) {
            f32x4 v;
            #pragma unroll
            for (int rr = 0; rr < 4; ++rr)
                v[rr] = (acc[m][n][rr] + acs) * inv;
            __builtin_nontemporal_store(v, (f32x4*)&ob[(size_t)tt * HOP + jbase + m * 16]);
        }
    }
}

// ---------- tail: out column t=4096 = (W·Y[:,4096] + ac[4095]) / 1024 ----------
__global__ __launch_bounds__(256, 2) void istft_tailY(
    const bf16* __restrict__ Xw, const bf16* __restrict__ Wt,
    const float* __restrict__ acv, float* __restrict__ out)
{
    __shared__ float xf[1024];
    const int b = blockIdx.x, tid = threadIdx.x;
    const bf16* xr = Xw + (((size_t)b * XROWS + 4096) << 10);   // Y[:,4096]
    {
        bf16x4 v = *(const bf16x4*)&xr[tid * 4];
        xf[tid * 4 + 0] = (float)v[0]; xf[tid * 4 + 1] = (float)v[1];
        xf[tid * 4 + 2] = (float)v[2]; xf[tid * 4 + 3] = (float)v[3];
    }
    __syncthreads();
    const float acs = acv[b * T_SZ + 4095];
    float s0 = 0.f, s1 = 0.f;
    const bf16* w0 = Wt + ((size_t)tid << 10);
    const bf16* w1 = Wt + ((size_t)(tid + 256) << 10);
    for (int kc = 0; kc < 128; ++kc) {
        bf16x8 av = *(const bf16x8*)&w0[kc * 8];
        bf16x8 cv = *(const bf16x8*)&w1[kc * 8];
        #pragma unroll
        for (int e = 0; e < 8; ++e) {
            const float xv = xf[kc * 8 + e];
            s0 += xv * (float)av[e];
            s1 += xv * (float)cv[e];
        }
    }
    float* ob = out + (size_t)b * OUT_LEN + (size_t)4096 * HOP;
    ob[tid]       = (s0 + acs) * (1.f / 1024.f);
    ob[tid + 256] = (s1 + acs) * (1.f / 1024.f);
}

// ---------- fallback (round-2 kernel, no workspace needed) ----------
#define LDBL 40
__global__ __launch_bounds__(256, 2) void istft_fused_legacy(
    const float* __restrict__ magn, const float* __restrict__ phase,
    const float* __restrict__ acv,
    const float* __restrict__ rk,  const float* __restrict__ ik,
    float* __restrict__ out)
{
    __shared__ __attribute__((aligned(16))) bf16 As[2][128 * LDBL];
    __shared__ __attribute__((aligned(16))) bf16 Bs[2][129 * LDBL];
    const int tid = threadIdx.x;
    const int w = tid >> 6, l = tid & 63;
    const int bid = blockIdx.x;
    const int xcd = bid & 7, q = bid >> 3;
    const int jt = q & 7, pgrp = q >> 3;
    const int pnl = pgrp * 8 + xcd;
    const int b = pnl / NTT33, tt0 = pnl - b * NTT33;
    const int j0 = jt * 64, t0 = tt0 * 128;
    const float* xm = magn  + (size_t)b * NFREQ * T_SZ;
    const float* xp = phase + (size_t)b * NFREQ * T_SZ;
    const int jrow = tid >> 3, fc = (tid & 7) * 4;
    const int f0 = (tid >> 5) * 4, tl = tid & 31;
    f32x4 areg[4]; float vreg[4][4]; float rz = 0.f;
    f32x4 acc[8][2];
    #pragma unroll
    for (int i = 0; i < 8; ++i)
        #pragma unroll
        for (int j = 0; j < 2; ++j) acc[i][j] = (f32x4){0.f, 0.f, 0.f, 0.f};
    const int nbase = w * 32;
    auto loadA = [&](int ks) {
        const int k0 = ks * 32;
        const float* wsrc = (k0 < NFREQ) ? (rk + k0) : (ik + (k0 - NFREQ));
        #pragma unroll
        for (int i = 0; i < 4; ++i) {
            const int jr = jrow + 32 * i;
            const int j = (jr < 64) ? (j0 + jr) : (j0 + 448 + jr);
            areg[i] = *(const f32x4*)&wsrc[(size_t)j * NFREQ + fc];
        }
    };
    auto writeA = [&](int p) {
        #pragma unroll
        for (int i = 0; i < 4; ++i) {
            bf16x4 v;
            v[0] = (bf16)areg[i][0]; v[1] = (bf16)areg[i][1];
            v[2] = (bf16)areg[i][2]; v[3] = (bf16)areg[i][3];
            *(bf16x4*)&As[p][(jrow + 32 * i) * LDBL + fc] = v;
        }
    };
    auto loadB = [&](int ks) {
        const int k0 = ks * 32;
        const float* xbp = (k0 < NFREQ) ? (xm + (size_t)k0 * T_SZ)
                                        : (xp + (size_t)(k0 - NFREQ) * T_SZ);
        #pragma unroll
        for (int i = 0; i < 4; ++i) {
            if (t0 + 32 * i + 32 <= T_SZ) {
                #pragma unroll
                for (int fj = 0; fj < 4; ++fj)
                    vreg[fj][i] = xbp[(size_t)(f0 + fj) * T_SZ + t0 + tl + 32 * i];
            } else {
                #pragma unroll
                for (int fj = 0; fj < 4; ++fj) vreg[fj][i] = 0.f;
            }
        }
        if (tid < 32) rz = (t0 >= 1) ? xbp[(size_t)tid * T_SZ + (t0 - 1)] : 0.f;
    };
    auto writeB = [&](int p) {
        #pragma unroll
        for (int i = 0; i < 4; ++i) {
            bf16x4 v;
            v[0] = (bf16)vreg[0][i]; v[1] = (bf16)vreg[1][i];
            v[2] = (bf16)vreg[2][i]; v[3] = (bf16)vreg[3][i];
            *(bf16x4*)&Bs[p][(1 + tl + 32 * i) * LDBL + f0] = v;
        }
        if (tid < 32) Bs[p][tid] = (bf16)rz;
    };
    loadA(0); loadB(0); writeA(0); writeB(0);
    __syncthreads();
    int p = 0;
    for (int ks = 0; ks < 32; ++ks) {
        if (ks + 1 < 32) { loadA(ks + 1); loadB(ks + 1); }
        bf16x8 af[8], blv[2], bhv[2];
        #pragma unroll
        for (int mi = 0; mi < 8; ++mi)
            af[mi] = *(const bf16x8*)&As[p][(mi * 16 + (l & 15)) * LDBL + (l >> 4) * 8];
        #pragma unroll
        for (int ni = 0; ni < 2; ++ni) {
            const int rb = nbase + ni * 16 + (l & 15);
            bhv[ni] = *(const bf16x8*)&Bs[p][rb * LDBL + (l >> 4) * 8];
            blv[ni] = *(const bf16x8*)&Bs[p][(rb + 1) * LDBL + (l >> 4) * 8];
        }
        #pragma unroll
        for (int ni = 0; ni < 2; ++ni)
            #pragma unroll
            for (int mi = 0; mi < 4; ++mi) {
                acc[mi][ni] = __builtin_amdgcn_mfma_f32_16x16x32_bf16(af[mi], blv[ni], acc[mi][ni], 0, 0, 0);
                acc[mi + 4][ni] = __builtin_amdgcn_mfma_f32_16x16x32_bf16(af[mi + 4], bhv[ni], acc[mi + 4][ni], 0, 0, 0);
            }
        if (ks + 1 < 32) { writeA(p ^ 1); writeB(p ^ 1); }
        __syncthreads();
        p ^= 1;
    }
    const float inv = 1.0f / 1024.0f;
    float* ob = out + (size_t)b * OUT_LEN;
    const float* acb = acv + (size_t)b * T_SZ;
    #pragma unroll
    for (int ni = 0; ni < 2; ++ni) {
        const int tt = t0 + nbase + ni * 16 + (l & 15);
        if (tt <= T_SZ) {
            float acs = 0.f;
            if (tt < T_SZ) acs += acb[tt];
            if (tt >= 1)   acs += acb[tt - 1];
            #pragma unroll
            for (int mi = 0; mi < 4; ++mi) {
                const int jl = j0 + mi * 16 + (l >> 4) * 4;
                f32x4 v;
                #pragma unroll
                for (int rr = 0; rr < 4; ++rr)
                    v[rr] = (acc[mi][ni][rr] + acc[mi + 4][ni][rr] + acs) * inv;
                __builtin_nontemporal_store(v, (f32x4*)&ob[(size_t)tt * HOP + jl]);
            }
        }
    }
}

extern "C" void kernel_launch(void* const* d_in, const int* in_sizes, int n_in,
                              void* d_out, int out_size, void* d_ws, size_t ws_size,
                              hipStream_t stream) {
    const float* magn  = (const float*)d_in[0];
    const float* phase = (const float*)d_in[1];
    const float* ac    = (const float*)d_in[2];
    const float* rk    = (const float*)d_in[3];
    const float* ik    = (const float*)d_in[4];
    float* out = (float*)d_out;

    if (ws_size >= WS_NEED) {
        bf16* Xw = (bf16*)d_ws;
        bf16* Wt = Xw + XW_ELEMS;
        cvt_w<<<512, 256, 0, stream>>>(rk, ik, Wt);
        cvt_x<<<8192, 256, 0, stream>>>(magn, phase, Xw);
        istft_gemmY2<<<2048, 256, 0, stream>>>(Xw, Wt, ac, out);
        istft_tailY<<<16, 256, 0, stream>>>(Xw, Wt, ac, out);
    } else {
        istft_fused_legacy<<<528 * 8, 256, 0, stream>>>(magn, phase, ac, rk, ik, out);
    }
}

// Round 11
// 181.713 us; speedup vs baseline: 1.1299x; 1.1299x over previous
//
#include <hip/hip_runtime.h>
#include <hip/hip_bf16.h>

typedef __bf16 bf16;
typedef __bf16 bf16x4 __attribute__((ext_vector_type(4)));
typedef __bf16 bf16x8 __attribute__((ext_vector_type(8)));
typedef float  f32x4  __attribute__((ext_vector_type(4)));

#define T_SZ   4096
#define NFREQ  512
#define HOP    512
#define OUT_LEN 2097664   // 4097 * 512
#define NTT33  33
#define XROWS  4097       // Xw row t holds Y[:,t], t in [0,4096]

#define XW_ELEMS ((size_t)16 * XROWS * 1024)
#define WT_ELEMS ((size_t)512 * 1024)
#define WS_NEED  ((XW_ELEMS + WT_ELEMS) * 2)

#define SB()  __builtin_amdgcn_sched_barrier(0)

__device__ __forceinline__ void gl16(const void* g, void* l) {
    __builtin_amdgcn_global_load_lds(
        (const __attribute__((address_space(1))) void*)g,
        (__attribute__((address_space(3))) void*)l, 16, 0, 0);
}

// Symmetry: W[j+512,c] = (-1)^(c+1) W[j,c].  With Y[k,t] = x[k,t] + s_k x[k,t-1],
// s_k = (c odd ? +1 : -1), c = k mod 512:  out[t*512+j] = (W[j,:]·Y[:,t] + ac[t] + ac[t-1])/1024.
// Single 512x1024xT GEMM — half the FLOPs of the lo/hi formulation.

// ---------- Wt[j][k] = k<512 ? rk[j][k] : ik[j][k-512], j in [0,512) ----------
__global__ __launch_bounds__(256, 4) void cvt_w(const float* __restrict__ rk,
                                                const float* __restrict__ ik,
                                                bf16* __restrict__ Wt) {
    const int j  = blockIdx.x;           // 512
    const int k4 = threadIdx.x * 4;
    const float* s = (k4 < NFREQ) ? &rk[j * NFREQ + k4] : &ik[j * NFREQ + k4 - NFREQ];
    f32x4 v = *(const f32x4*)s;
    bf16x4 h;
    h[0] = (bf16)v[0]; h[1] = (bf16)v[1]; h[2] = (bf16)v[2]; h[3] = (bf16)v[3];
    *(bf16x4*)&Wt[((size_t)j << 10) + k4] = h;
}

// ---------- Xw[b][t][k] = Y[k,t]  (transpose + bf16 + the s_k combine) ----------
__global__ __launch_bounds__(256, 4) void cvt_x(const float* __restrict__ magn,
                                                const float* __restrict__ phase,
                                                bf16* __restrict__ Xw) {
    __shared__ float t2[64][133];        // cols 0..127 = x[t0..t0+127], col 128 = x[t0-1]
    const int tid = threadIdx.x;
    const int bid = blockIdx.x;
    const int kt  = bid & 15;            // k-tile of 64 (global k = kt*64 + f)
    const int tt  = (bid >> 4) & 31;     // t-tile of 128
    const int b   = bid >> 9;
    const float* srcb = (kt < 8 ? magn : phase)
                      + ((size_t)b * NFREQ + (kt & 7) * 64) * T_SZ + tt * 128;
    const int fr = tid >> 5;
    const int cc = (tid & 31) * 4;
    #pragma unroll
    for (int p = 0; p < 8; ++p) {
        const int f = fr + 8 * p;
        f32x4 v = *(const f32x4*)&srcb[(size_t)f * T_SZ + cc];
        t2[f][cc + 0] = v[0]; t2[f][cc + 1] = v[1];
        t2[f][cc + 2] = v[2]; t2[f][cc + 3] = v[3];
    }
    if (tid < 64)
        t2[tid][128] = (tt > 0) ? srcb[(size_t)tid * T_SZ - 1] : 0.f;
    __syncthreads();

    const int koff = (tid & 7) * 8;      // local k base
    bf16* dstb = Xw + (((size_t)b * XROWS + tt * 128) << 10) + kt * 64 + koff;
    #pragma unroll
    for (int q = 0; q < 4; ++q) {
        const int tr  = (tid >> 3) + 32 * q;
        const int im1 = tr ? (tr - 1) : 128;
        bf16x8 o;
        #pragma unroll
        for (int ki = 0; ki < 8; ++ki) {
            const int f = koff + ki;
            const float sgn = (f & 1) ? 1.f : -1.f;   // c parity == f parity
            o[ki] = (bf16)(t2[f][tr] + sgn * t2[f][im1]);
        }
        *(bf16x8*)&dstb[(size_t)tr << 10] = o;
    }
    // row t = 4096: Y = s_k * x[k, 4095]  (x[:,4096] = 0)
    if (tt == 31 && tid < 8) {
        bf16x8 o;
        #pragma unroll
        for (int ki = 0; ki < 8; ++ki) {
            const int f = tid * 8 + ki;
            const float sgn = (f & 1) ? 1.f : -1.f;
            o[ki] = (bf16)(sgn * t2[f][127]);
        }
        *(bf16x8*)&Xw[(((size_t)b * XROWS + 4096) << 10) + kt * 64 + tid * 8] = o;
    }
}

// ---------- main GEMM: 128j x 128t tile, 4 waves, TRIPLE-buffer counted-vmcnt ----------
// A-tile: 128 rows = Wt[j0+r].  B-tile row r = Y[:, t0+r] (clamped to 4096; tile 32 = t=4096 col).
// Buffers rotate mod 3: step ks reads buf ks%3, stages tile ks+2 into buf (ks+2)%3 == buf of
// step ks-1 (its reads retired before the last barrier). End-of-step waits vmcnt(4): the
// awaited loads are one full K-step old -> HBM latency fully hidden, no vmcnt(0) drain.
// Swizzle both-sides: 16B slot' = slot ^ ((row ^ row>>2)&3); LDS linear dest,
// gl16 SOURCE pre-swizzled, ds_read applies the same XOR.
__global__ __launch_bounds__(256, 3) void istft_gemmY3(
    const bf16* __restrict__ Xw, const bf16* __restrict__ Wt,
    const float* __restrict__ acv, float* __restrict__ out)
{
    __shared__ __attribute__((aligned(16))) bf16 As[3][128 * 32];
    __shared__ __attribute__((aligned(16))) bf16 Bs[3][128 * 32];

    const int tid = threadIdx.x;
    const int w   = tid >> 6;      // 4 waves: wr = w>>1 (j half), wc = w&1 (t half)
    const int l   = tid & 63;
    const int wr  = w >> 1, wc = w & 1;
    const int c15 = l & 15, c4 = l >> 4;

    const int bid = blockIdx.x;    // 2112 = 528 panels x 4 j-tiles; panel -> xcd = bid&7
    const int xcd = bid & 7;
    const int idx = bid >> 3;      // 0..263
    const int jt  = idx & 3;
    const int png = idx >> 2;      // 0..65
    const int pnl = png * 8 + xcd; // 0..527 (16 b x 33 t-tiles)
    const int b   = pnl / NTT33;
    const int tt0 = pnl - b * NTT33;
    const int j0  = jt * 128;
    const int t0  = tt0 * 128;     // t0 <= 4096
    const size_t xb = (size_t)b * XROWS;

    // staging: 64B rows of 4 slots; lane -> row 16w+(l>>2), slot l&3, pre-swizzled src slot
    const int ssrc = ((l & 3) ^ ((l >> 2) & 3) ^ ((l >> 4) & 3)) * 8;
    const int srow = 16 * w + (l >> 2);                 // 0..63 per sweep

    const size_t asrc0 = ((size_t)(j0 + srow)) << 10;        // A rows 0..63
    const size_t asrc1 = ((size_t)(j0 + 64 + srow)) << 10;   // A rows 64..127
    int tq0 = t0 + srow;        if (tq0 > 4096) tq0 = 4096;  // clamp (tile 32 only)
    int tq1 = t0 + 64 + srow;   if (tq1 > 4096) tq1 = 4096;
    const size_t bsrc0 = (xb + tq0) << 10;
    const size_t bsrc1 = (xb + tq1) << 10;

    auto stage = [&](int p, int ks) {
        const int k0 = ks * 32;
        gl16(Wt + asrc0 + k0 + ssrc, &As[p][(16 * w) * 32]);
        gl16(Wt + asrc1 + k0 + ssrc, &As[p][(64 + 16 * w) * 32]);
        gl16(Xw + bsrc0 + k0 + ssrc, &Bs[p][(16 * w) * 32]);
        gl16(Xw + bsrc1 + k0 + ssrc, &Bs[p][(64 + 16 * w) * 32]);
    };

    // ac prefetch (k-independent): hides the ~900-cy scalar-load latency under the GEMM
    const float* acb = acv + (size_t)b * T_SZ;
    float acs_r[4];
    #pragma unroll
    for (int n = 0; n < 4; ++n) {
        const int tt = t0 + wc * 64 + n * 16 + c15;     // 0..4223
        const float a0 = (tt < T_SZ) ? acb[tt] : 0.f;
        const float a1 = (tt >= 1 && tt <= T_SZ) ? acb[tt - 1] : 0.f;
        acs_r[n] = a0 + a1;
    }

    f32x4 acc[4][4];
    #pragma unroll
    for (int i = 0; i < 4; ++i)
        #pragma unroll
        for (int j = 0; j < 4; ++j)
            acc[i][j] = (f32x4){0.f, 0.f, 0.f, 0.f};

    bf16x8 a[4], bb[4];
    auto rdFrags = [&](int p) {
        #pragma unroll
        for (int m = 0; m < 4; ++m) {
            const int r = wr * 64 + m * 16 + c15;            // 0..127
            const int s = ((c4 ^ r ^ (r >> 2)) & 3) * 8;
            a[m] = *(const bf16x8*)&As[p][r * 32 + s];
        }
        #pragma unroll
        for (int n = 0; n < 4; ++n) {
            const int r = wc * 64 + n * 16 + c15;            // 0..127
            const int s = ((c4 ^ r ^ (r >> 2)) & 3) * 8;
            bb[n] = *(const bf16x8*)&Bs[p][r * 32 + s];
        }
    };

    // prologue: tiles 0,1 in flight; wait tile 0 only (vmcnt leaves tile 1's 4 loads)
    stage(0, 0);
    stage(1, 1);
    asm volatile("s_waitcnt vmcnt(4)" ::: "memory");
    SB(); __builtin_amdgcn_s_barrier(); SB();

    int cur = 0, nxt2 = 2;
    for (int ks = 0; ks < 32; ++ks) {
        if (ks + 2 < 32) stage(nxt2, ks + 2);   // into the buffer read at step ks-1
        rdFrags(cur);                           // compiler inserts fine-grained lgkmcnt
        #pragma unroll
        for (int m = 0; m < 4; ++m)
            #pragma unroll
            for (int n = 0; n < 4; ++n)
                acc[m][n] = __builtin_amdgcn_mfma_f32_16x16x32_bf16(
                    a[m], bb[n], acc[m][n], 0, 0, 0);
        // wait only for the loads issued LAST step (tile ks+1) - one K-step old
        if (ks < 30) asm volatile("s_waitcnt vmcnt(4)" ::: "memory");
        else         asm volatile("s_waitcnt vmcnt(0)" ::: "memory");
        SB(); __builtin_amdgcn_s_barrier(); SB();
        cur  = (cur == 2)  ? 0 : cur + 1;
        nxt2 = (nxt2 == 2) ? 0 : nxt2 + 1;
    }

    // epilogue: out[tt*512+j] = (acc + ac[tt] + ac[tt-1]) / 1024, masked at tt>4096
    const float inv = 1.0f / 1024.0f;
    float* ob = out + (size_t)b * OUT_LEN;
    const int jbase = j0 + wr * 64 + c4 * 4;
    #pragma unroll
    for (int n = 0; n < 4; ++n) {
        const int tt = t0 + wc * 64 + n * 16 + c15;
        if (tt <= 4096) {
            #pragma unroll
            for (int m = 0; m < 4; ++m) {
                f32x4 v;
                #pragma unroll
                for (int rr = 0; rr < 4; ++rr)
                    v[rr] = (acc[m][n][rr] + acs_r[n]) * inv;
                __builtin_nontemporal_store(v, (f32x4*)&ob[(size_t)tt * HOP + jbase + m * 16]);
            }
        }
    }
}

// ---------- fallback (round-2 kernel, no workspace needed) ----------
#define LDBL 40
__global__ __launch_bounds__(256, 2) void istft_fused_legacy(
    const float* __restrict__ magn, const float* __restrict__ phase,
    const float* __restrict__ acv,
    const float* __restrict__ rk,  const float* __restrict__ ik,
    float* __restrict__ out)
{
    __shared__ __attribute__((aligned(16))) bf16 As[2][128 * LDBL];
    __shared__ __attribute__((aligned(16))) bf16 Bs[2][129 * LDBL];
    const int tid = threadIdx.x;
    const int w = tid >> 6, l = tid & 63;
    const int bid = blockIdx.x;
    const int xcd = bid & 7, q = bid >> 3;
    const int jt = q & 7, pgrp = q >> 3;
    const int pnl = pgrp * 8 + xcd;
    const int b = pnl / NTT33, tt0 = pnl - b * NTT33;
    const int j0 = jt * 64, t0 = tt0 * 128;
    const float* xm = magn  + (size_t)b * NFREQ * T_SZ;
    const float* xp = phase + (size_t)b * NFREQ * T_SZ;
    const int jrow = tid >> 3, fc = (tid & 7) * 4;
    const int f0 = (tid >> 5) * 4, tl = tid & 31;
    f32x4 areg[4]; float vreg[4][4]; float rz = 0.f;
    f32x4 acc[8][2];
    #pragma unroll
    for (int i = 0; i < 8; ++i)
        #pragma unroll
        for (int j = 0; j < 2; ++j) acc[i][j] = (f32x4){0.f, 0.f, 0.f, 0.f};
    const int nbase = w * 32;
    auto loadA = [&](int ks) {
        const int k0 = ks * 32;
        const float* wsrc = (k0 < NFREQ) ? (rk + k0) : (ik + (k0 - NFREQ));
        #pragma unroll
        for (int i = 0; i < 4; ++i) {
            const int jr = jrow + 32 * i;
            const int j = (jr < 64) ? (j0 + jr) : (j0 + 448 + jr);
            areg[i] = *(const f32x4*)&wsrc[(size_t)j * NFREQ + fc];
        }
    };
    auto writeA = [&](int p) {
        #pragma unroll
        for (int i = 0; i < 4; ++i) {
            bf16x4 v;
            v[0] = (bf16)areg[i][0]; v[1] = (bf16)areg[i][1];
            v[2] = (bf16)areg[i][2]; v[3] = (bf16)areg[i][3];
            *(bf16x4*)&As[p][(jrow + 32 * i) * LDBL + fc] = v;
        }
    };
    auto loadB = [&](int ks) {
        const int k0 = ks * 32;
        const float* xbp = (k0 < NFREQ) ? (xm + (size_t)k0 * T_SZ)
                                        : (xp + (size_t)(k0 - NFREQ) * T_SZ);
        #pragma unroll
        for (int i = 0; i < 4; ++i) {
            if (t0 + 32 * i + 32 <= T_SZ) {
                #pragma unroll
                for (int fj = 0; fj < 4; ++fj)
                    vreg[fj][i] = xbp[(size_t)(f0 + fj) * T_SZ + t0 + tl + 32 * i];
            } else {
                #pragma unroll
                for (int fj = 0; fj < 4; ++fj) vreg[fj][i] = 0.f;
            }
        }
        if (tid < 32) rz = (t0 >= 1) ? xbp[(size_t)tid * T_SZ + (t0 - 1)] : 0.f;
    };
    auto writeB = [&](int p) {
        #pragma unroll
        for (int i = 0; i < 4; ++i) {
            bf16x4 v;
            v[0] = (bf16)vreg[0][i]; v[1] = (bf16)vreg[1][i];
            v[2] = (bf16)vreg[2][i]; v[3] = (bf16)vreg[3][i];
            *(bf16x4*)&Bs[p][(1 + tl + 32 * i) * LDBL + f0] = v;
        }
        if (tid < 32) Bs[p][tid] = (bf16)rz;
    };
    loadA(0); loadB(0); writeA(0); writeB(0);
    __syncthreads();
    int p = 0;
    for (int ks = 0; ks < 32; ++ks) {
        if (ks + 1 < 32) { loadA(ks + 1); loadB(ks + 1); }
        bf16x8 af[8], blv[2], bhv[2];
        #pragma unroll
        for (int mi = 0; mi < 8; ++mi)
            af[mi] = *(const bf16x8*)&As[p][(mi * 16 + (l & 15)) * LDBL + (l >> 4) * 8];
        #pragma unroll
        for (int ni = 0; ni < 2; ++ni) {
            const int rb = nbase + ni * 16 + (l & 15);
            bhv[ni] = *(const bf16x8*)&Bs[p][rb * LDBL + (l >> 4) * 8];
            blv[ni] = *(const bf16x8*)&Bs[p][(rb + 1) * LDBL + (l >> 4) * 8];
        }
        #pragma unroll
        for (int ni = 0; ni < 2; ++ni)
            #pragma unroll
            for (int mi = 0; mi < 4; ++mi) {
                acc[mi][ni] = __builtin_amdgcn_mfma_f32_16x16x32_bf16(af[mi], blv[ni], acc[mi][ni], 0, 0, 0);
                acc[mi + 4][ni] = __builtin_amdgcn_mfma_f32_16x16x32_bf16(af[mi + 4], bhv[ni], acc[mi + 4][ni], 0, 0, 0);
            }
        if (ks + 1 < 32) { writeA(p ^ 1); writeB(p ^ 1); }
        __syncthreads();
        p ^= 1;
    }
    const float inv = 1.0f / 1024.0f;
    float* ob = out + (size_t)b * OUT_LEN;
    const float* acb = acv + (size_t)b * T_SZ;
    #pragma unroll
    for (int ni = 0; ni < 2; ++ni) {
        const int tt = t0 + nbase + ni * 16 + (l & 15);
        if (tt <= T_SZ) {
            float acs = 0.f;
            if (tt < T_SZ) acs += acb[tt];
            if (tt >= 1)   acs += acb[tt - 1];
            #pragma unroll
            for (int mi = 0; mi < 4; ++mi) {
                const int jl = j0 + mi * 16 + (l >> 4) * 4;
                f32x4 v;
                #pragma unroll
                for (int rr = 0; rr < 4; ++rr)
                    v[rr] = (acc[mi][ni][rr] + acc[mi + 4][ni][rr] + acs) * inv;
                __builtin_nontemporal_store(v, (f32x4*)&ob[(size_t)tt * HOP + jl]);
            }
        }
    }
}

extern "C" void kernel_launch(void* const* d_in, const int* in_sizes, int n_in,
                              void* d_out, int out_size, void* d_ws, size_t ws_size,
                              hipStream_t stream) {
    const float* magn  = (const float*)d_in[0];
    const float* phase = (const float*)d_in[1];
    const float* ac    = (const float*)d_in[2];
    const float* rk    = (const float*)d_in[3];
    const float* ik    = (const float*)d_in[4];
    float* out = (float*)d_out;

    if (ws_size >= WS_NEED) {
        bf16* Xw = (bf16*)d_ws;
        bf16* Wt = Xw + XW_ELEMS;
        cvt_w<<<512, 256, 0, stream>>>(rk, ik, Wt);
        cvt_x<<<8192, 256, 0, stream>>>(magn, phase, Xw);
        istft_gemmY3<<<2112, 256, 0, stream>>>(Xw, Wt, ac, out);
    } else {
        istft_fused_legacy<<<528 * 8, 256, 0, stream>>>(magn, phase, ac, rk, ik, out);
    }
}

// Round 12
// 181.114 us; speedup vs baseline: 1.1337x; 1.0033x over previous
//
#include <hip/hip_runtime.h>
#include <hip/hip_bf16.h>

typedef __bf16 bf16;
typedef __bf16 bf16x4 __attribute__((ext_vector_type(4)));
typedef __bf16 bf16x8 __attribute__((ext_vector_type(8)));
typedef float  f32x4  __attribute__((ext_vector_type(4)));

#define T_SZ   4096
#define NFREQ  512
#define HOP    512
#define OUT_LEN 2097664   // 4097 * 512
#define NTT33  33
#define XROWS  4097       // Xw row t holds Y[:,t], t in [0,4096]

#define XW_ELEMS ((size_t)16 * XROWS * 1024)
#define WT_ELEMS ((size_t)512 * 1024)
#define WS_NEED  ((XW_ELEMS + WT_ELEMS) * 2)

__device__ __forceinline__ void gl16(const void* g, void* l) {
    __builtin_amdgcn_global_load_lds(
        (const __attribute__((address_space(1))) void*)g,
        (__attribute__((address_space(3))) void*)l, 16, 0, 0);
}

// Symmetry: W[j+512,c] = (-1)^(c+1) W[j,c].  With Y[k,t] = x[k,t] + s_k x[k,t-1],
// s_k = (c odd ? +1 : -1), c = k mod 512:  out[t*512+j] = (W[j,:]·Y[:,t] + ac[t] + ac[t-1])/1024.
// Single 512x1024x(T+1) GEMM — half the FLOPs of the lo/hi formulation; the t=4096
// output column is a normal GEMM column (Y[:,4096] = s_k x[:,4095]).

// ---------- Wt[j][k] = k<512 ? rk[j][k] : ik[j][k-512], j in [0,512) ----------
__global__ __launch_bounds__(256, 4) void cvt_w(const float* __restrict__ rk,
                                                const float* __restrict__ ik,
                                                bf16* __restrict__ Wt) {
    const int j  = blockIdx.x;           // 512
    const int k4 = threadIdx.x * 4;
    const float* s = (k4 < NFREQ) ? &rk[j * NFREQ + k4] : &ik[j * NFREQ + k4 - NFREQ];
    f32x4 v = *(const f32x4*)s;
    bf16x4 h;
    h[0] = (bf16)v[0]; h[1] = (bf16)v[1]; h[2] = (bf16)v[2]; h[3] = (bf16)v[3];
    *(bf16x4*)&Wt[((size_t)j << 10) + k4] = h;
}

// ---------- Xw[b][t][k] = Y[k,t]  (transpose + bf16 + the s_k combine) ----------
__global__ __launch_bounds__(256, 4) void cvt_x(const float* __restrict__ magn,
                                                const float* __restrict__ phase,
                                                bf16* __restrict__ Xw) {
    __shared__ float t2[64][133];        // cols 0..127 = x[t0..t0+127], col 128 = x[t0-1]
    const int tid = threadIdx.x;
    const int bid = blockIdx.x;
    const int kt  = bid & 15;            // k-tile of 64 (global k = kt*64 + f)
    const int tt  = (bid >> 4) & 31;     // t-tile of 128
    const int b   = bid >> 9;
    const float* srcb = (kt < 8 ? magn : phase)
                      + ((size_t)b * NFREQ + (kt & 7) * 64) * T_SZ + tt * 128;
    const int fr = tid >> 5;
    const int cc = (tid & 31) * 4;
    #pragma unroll
    for (int p = 0; p < 8; ++p) {
        const int f = fr + 8 * p;
        f32x4 v = *(const f32x4*)&srcb[(size_t)f * T_SZ + cc];
        t2[f][cc + 0] = v[0]; t2[f][cc + 1] = v[1];
        t2[f][cc + 2] = v[2]; t2[f][cc + 3] = v[3];
    }
    if (tid < 64)
        t2[tid][128] = (tt > 0) ? srcb[(size_t)tid * T_SZ - 1] : 0.f;
    __syncthreads();

    const int koff = (tid & 7) * 8;      // local k base
    bf16* dstb = Xw + (((size_t)b * XROWS + tt * 128) << 10) + kt * 64 + koff;
    #pragma unroll
    for (int q = 0; q < 4; ++q) {
        const int tr  = (tid >> 3) + 32 * q;
        const int im1 = tr ? (tr - 1) : 128;
        bf16x8 o;
        #pragma unroll
        for (int ki = 0; ki < 8; ++ki) {
            const int f = koff + ki;
            const float sgn = (f & 1) ? 1.f : -1.f;   // c parity == f parity
            o[ki] = (bf16)(t2[f][tr] + sgn * t2[f][im1]);
        }
        *(bf16x8*)&dstb[(size_t)tr << 10] = o;
    }
    // row t = 4096: Y = s_k * x[k, 4095]  (x[:,4096] = 0)
    if (tt == 31 && tid < 8) {
        bf16x8 o;
        #pragma unroll
        for (int ki = 0; ki < 8; ++ki) {
            const int f = tid * 8 + ki;
            const float sgn = (f & 1) ? 1.f : -1.f;
            o[ki] = (bf16)(sgn * t2[f][127]);
        }
        *(bf16x8*)&Xw[(((size_t)b * XROWS + 4096) << 10) + kt * 64 + tid * 8] = o;
    }
}

// ---------- main GEMM: 128j x 128t tile, 4 waves, 4 blocks/CU, 2-barrier loop ----------
// R10's proven config + R11's tail-free grid (2112 blocks, clamped B, masked stores)
// + ac prefetch. A-tile: 128 rows = Wt[j0+r]. B-tile row r = Y[:, t0+r] (clamped to 4096).
// Swizzle both-sides: 16B slot' = slot ^ ((row ^ row>>2)&3); LDS linear dest,
// gl16 SOURCE pre-swizzled, ds_read applies the same XOR.
__global__ __launch_bounds__(256, 4) void istft_gemmY4(
    const bf16* __restrict__ Xw, const bf16* __restrict__ Wt,
    const float* __restrict__ acv, float* __restrict__ out)
{
    __shared__ __attribute__((aligned(16))) bf16 As[2][128 * 32];
    __shared__ __attribute__((aligned(16))) bf16 Bs[2][128 * 32];

    const int tid = threadIdx.x;
    const int w   = tid >> 6;      // 4 waves: wr = w>>1 (j half), wc = w&1 (t half)
    const int l   = tid & 63;
    const int wr  = w >> 1, wc = w & 1;
    const int c15 = l & 15, c4 = l >> 4;

    const int bid = blockIdx.x;    // 2112 = 528 panels x 4 j-tiles; panel -> xcd = bid&7
    const int xcd = bid & 7;
    const int idx = bid >> 3;      // 0..263
    const int jt  = idx & 3;
    const int png = idx >> 2;      // 0..65
    const int pnl = png * 8 + xcd; // 0..527 (16 b x 33 t-tiles)
    const int b   = pnl / NTT33;
    const int tt0 = pnl - b * NTT33;
    const int j0  = jt * 128;
    const int t0  = tt0 * 128;     // t0 <= 4096
    const size_t xb = (size_t)b * XROWS;

    // staging: 64B rows of 4 slots; lane -> row 16w+(l>>2), slot l&3, pre-swizzled src slot
    const int ssrc = ((l & 3) ^ ((l >> 2) & 3) ^ ((l >> 4) & 3)) * 8;
    const int srow = 16 * w + (l >> 2);                 // 0..63 per sweep

    const size_t asrc0 = ((size_t)(j0 + srow)) << 10;        // A rows 0..63
    const size_t asrc1 = ((size_t)(j0 + 64 + srow)) << 10;   // A rows 64..127
    int tq0 = t0 + srow;        if (tq0 > 4096) tq0 = 4096;  // clamp (tile 32 only)
    int tq1 = t0 + 64 + srow;   if (tq1 > 4096) tq1 = 4096;
    const size_t bsrc0 = (xb + tq0) << 10;
    const size_t bsrc1 = (xb + tq1) << 10;

    auto stage = [&](int p, int ks) {
        const int k0 = ks * 32;
        gl16(Wt + asrc0 + k0 + ssrc, &As[p][(16 * w) * 32]);
        gl16(Wt + asrc1 + k0 + ssrc, &As[p][(64 + 16 * w) * 32]);
        gl16(Xw + bsrc0 + k0 + ssrc, &Bs[p][(16 * w) * 32]);
        gl16(Xw + bsrc1 + k0 + ssrc, &Bs[p][(64 + 16 * w) * 32]);
    };

    // ac prefetch (k-independent): hides the scalar-load latency under the K-loop
    const float* acb = acv + (size_t)b * T_SZ;
    float acs_r[4];
    #pragma unroll
    for (int n = 0; n < 4; ++n) {
        const int tt = t0 + wc * 64 + n * 16 + c15;     // 0..4223
        const float a0 = (tt < T_SZ) ? acb[tt] : 0.f;
        const float a1 = (tt >= 1 && tt <= T_SZ) ? acb[tt - 1] : 0.f;
        acs_r[n] = a0 + a1;
    }

    f32x4 acc[4][4];
    #pragma unroll
    for (int i = 0; i < 4; ++i)
        #pragma unroll
        for (int j = 0; j < 4; ++j)
            acc[i][j] = (f32x4){0.f, 0.f, 0.f, 0.f};

    bf16x8 a[4], bb[4];
    auto rdFrags = [&](int p) {
        #pragma unroll
        for (int m = 0; m < 4; ++m) {
            const int r = wr * 64 + m * 16 + c15;            // 0..127
            const int s = ((c4 ^ r ^ (r >> 2)) & 3) * 8;
            a[m] = *(const bf16x8*)&As[p][r * 32 + s];
        }
        #pragma unroll
        for (int n = 0; n < 4; ++n) {
            const int r = wc * 64 + n * 16 + c15;            // 0..127
            const int s = ((c4 ^ r ^ (r >> 2)) & 3) * 8;
            bb[n] = *(const bf16x8*)&Bs[p][r * 32 + s];
        }
    };

    stage(0, 0);
    __syncthreads();

    for (int ks = 0; ks < 32; ++ks) {
        const int P = ks & 1;
        if (ks + 1 < 32) stage(P ^ 1, ks + 1);   // issue next-tile loads first
        rdFrags(P);
        #pragma unroll
        for (int m = 0; m < 4; ++m)
            #pragma unroll
            for (int n = 0; n < 4; ++n)
                acc[m][n] = __builtin_amdgcn_mfma_f32_16x16x32_bf16(
                    a[m], bb[n], acc[m][n], 0, 0, 0);
        __syncthreads();   // drains staging loads; hidden by 4 blocks/CU
    }

    // epilogue: out[tt*512+j] = (acc + ac[tt] + ac[tt-1]) / 1024, masked at tt>4096
    const float inv = 1.0f / 1024.0f;
    float* ob = out + (size_t)b * OUT_LEN;
    const int jbase = j0 + wr * 64 + c4 * 4;
    #pragma unroll
    for (int n = 0; n < 4; ++n) {
        const int tt = t0 + wc * 64 + n * 16 + c15;
        if (tt <= 4096) {
            #pragma unroll
            for (int m = 0; m < 4; ++m) {
                f32x4 v;
                #pragma unroll
                for (int rr = 0; rr < 4; ++rr)
                    v[rr] = (acc[m][n][rr] + acs_r[n]) * inv;
                __builtin_nontemporal_store(v, (f32x4*)&ob[(size_t)tt * HOP + jbase + m * 16]);
            }
        }
    }
}

// ---------- fallback (round-2 kernel, no workspace needed) ----------
#define LDBL 40
__global__ __launch_bounds__(256, 2) void istft_fused_legacy(
    const float* __restrict__ magn, const float* __restrict__ phase,
    const float* __restrict__ acv,
    const float* __restrict__ rk,  const float* __restrict__ ik,
    float* __restrict__ out)
{
    __shared__ __attribute__((aligned(16))) bf16 As[2][128 * LDBL];
    __shared__ __attribute__((aligned(16))) bf16 Bs[2][129 * LDBL];
    const int tid = threadIdx.x;
    const int w = tid >> 6, l = tid & 63;
    const int bid = blockIdx.x;
    const int xcd = bid & 7, q = bid >> 3;
    const int jt = q & 7, pgrp = q >> 3;
    const int pnl = pgrp * 8 + xcd;
    const int b = pnl / NTT33, tt0 = pnl - b * NTT33;
    const int j0 = jt * 64, t0 = tt0 * 128;
    const float* xm = magn  + (size_t)b * NFREQ * T_SZ;
    const float* xp = phase + (size_t)b * NFREQ * T_SZ;
    const int jrow = tid >> 3, fc = (tid & 7) * 4;
    const int f0 = (tid >> 5) * 4, tl = tid & 31;
    f32x4 areg[4]; float vreg[4][4]; float rz = 0.f;
    f32x4 acc[8][2];
    #pragma unroll
    for (int i = 0; i < 8; ++i)
        #pragma unroll
        for (int j = 0; j < 2; ++j) acc[i][j] = (f32x4){0.f, 0.f, 0.f, 0.f};
    const int nbase = w * 32;
    auto loadA = [&](int ks) {
        const int k0 = ks * 32;
        const float* wsrc = (k0 < NFREQ) ? (rk + k0) : (ik + (k0 - NFREQ));
        #pragma unroll
        for (int i = 0; i < 4; ++i) {
            const int jr = jrow + 32 * i;
            const int j = (jr < 64) ? (j0 + jr) : (j0 + 448 + jr);
            areg[i] = *(const f32x4*)&wsrc[(size_t)j * NFREQ + fc];
        }
    };
    auto writeA = [&](int p) {
        #pragma unroll
        for (int i = 0; i < 4; ++i) {
            bf16x4 v;
            v[0] = (bf16)areg[i][0]; v[1] = (bf16)areg[i][1];
            v[2] = (bf16)areg[i][2]; v[3] = (bf16)areg[i][3];
            *(bf16x4*)&As[p][(jrow + 32 * i) * LDBL + fc] = v;
        }
    };
    auto loadB = [&](int ks) {
        const int k0 = ks * 32;
        const float* xbp = (k0 < NFREQ) ? (xm + (size_t)k0 * T_SZ)
                                        : (xp + (size_t)(k0 - NFREQ) * T_SZ);
        #pragma unroll
        for (int i = 0; i < 4; ++i) {
            if (t0 + 32 * i + 32 <= T_SZ) {
                #pragma unroll
                for (int fj = 0; fj < 4; ++fj)
                    vreg[fj][i] = xbp[(size_t)(f0 + fj) * T_SZ + t0 + tl + 32 * i];
            } else {
                #pragma unroll
                for (int fj = 0; fj < 4; ++fj) vreg[fj][i] = 0.f;
            }
        }
        if (tid < 32) rz = (t0 >= 1) ? xbp[(size_t)tid * T_SZ + (t0 - 1)] : 0.f;
    };
    auto writeB = [&](int p) {
        #pragma unroll
        for (int i = 0; i < 4; ++i) {
            bf16x4 v;
            v[0] = (bf16)vreg[0][i]; v[1] = (bf16)vreg[1][i];
            v[2] = (bf16)vreg[2][i]; v[3] = (bf16)vreg[3][i];
            *(bf16x4*)&Bs[p][(1 + tl + 32 * i) * LDBL + f0] = v;
        }
        if (tid < 32) Bs[p][tid] = (bf16)rz;
    };
    loadA(0); loadB(0); writeA(0); writeB(0);
    __syncthreads();
    int p = 0;
    for (int ks = 0; ks < 32; ++ks) {
        if (ks + 1 < 32) { loadA(ks + 1); loadB(ks + 1); }
        bf16x8 af[8], blv[2], bhv[2];
        #pragma unroll
        for (int mi = 0; mi < 8; ++mi)
            af[mi] = *(const bf16x8*)&As[p][(mi * 16 + (l & 15)) * LDBL + (l >> 4) * 8];
        #pragma unroll
        for (int ni = 0; ni < 2; ++ni) {
            const int rb = nbase + ni * 16 + (l & 15);
            bhv[ni] = *(const bf16x8*)&Bs[p][rb * LDBL + (l >> 4) * 8];
            blv[ni] = *(const bf16x8*)&Bs[p][(rb + 1) * LDBL + (l >> 4) * 8];
        }
        #pragma unroll
        for (int ni = 0; ni < 2; ++ni)
            #pragma unroll
            for (int mi = 0; mi < 4; ++mi) {
                acc[mi][ni] = __builtin_amdgcn_mfma_f32_16x16x32_bf16(af[mi], blv[ni], acc[mi][ni], 0, 0, 0);
                acc[mi + 4][ni] = __builtin_amdgcn_mfma_f32_16x16x32_bf16(af[mi + 4], bhv[ni], acc[mi + 4][ni], 0, 0, 0);
            }
        if (ks + 1 < 32) { writeA(p ^ 1); writeB(p ^ 1); }
        __syncthreads();
        p ^= 1;
    }
    const float inv = 1.0f / 1024.0f;
    float* ob = out + (size_t)b * OUT_LEN;
    const float* acb = acv + (size_t)b * T_SZ;
    #pragma unroll
    for (int ni = 0; ni < 2; ++ni) {
        const int tt = t0 + nbase + ni * 16 + (l & 15);
        if (tt <= T_SZ) {
            float acs = 0.f;
            if (tt < T_SZ) acs += acb[tt];
            if (tt >= 1)   acs += acb[tt - 1];
            #pragma unroll
            for (int mi = 0; mi < 4; ++mi) {
                const int jl = j0 + mi * 16 + (l >> 4) * 4;
                f32x4 v;
                #pragma unroll
                for (int rr = 0; rr < 4; ++rr)
                    v[rr] = (acc[mi][ni][rr] + acc[mi + 4][ni][rr] + acs) * inv;
                __builtin_nontemporal_store(v, (f32x4*)&ob[(size_t)tt * HOP + jl]);
            }
        }
    }
}

extern "C" void kernel_launch(void* const* d_in, const int* in_sizes, int n_in,
                              void* d_out, int out_size, void* d_ws, size_t ws_size,
                              hipStream_t stream) {
    const float* magn  = (const float*)d_in[0];
    const float* phase = (const float*)d_in[1];
    const float* ac    = (const float*)d_in[2];
    const float* rk    = (const float*)d_in[3];
    const float* ik    = (const float*)d_in[4];
    float* out = (float*)d_out;

    if (ws_size >= WS_NEED) {
        bf16* Xw = (bf16*)d_ws;
        bf16* Wt = Xw + XW_ELEMS;
        cvt_w<<<512, 256, 0, stream>>>(rk, ik, Wt);
        cvt_x<<<8192, 256, 0, stream>>>(magn, phase, Xw);
        istft_gemmY4<<<2112, 256, 0, stream>>>(Xw, Wt, ac, out);
    } else {
        istft_fused_legacy<<<528 * 8, 256, 0, stream>>>(magn, phase, ac, rk, ik, out);
    }
}